// Round 8
// baseline (485.476 us; speedup 1.0000x reference)
//
#include <hip/hip_runtime.h>

// Problem constants (fixed by reference)
constexpr int Bn = 4;
constexpr int Nn = 1024;
constexpr int Cn = 768;
constexpr int Hn = 12;
constexpr int Dn = 64;
constexpr float SCALE_Q = 0.125f;          // D^-0.5
constexpr int SEG = Bn * Nn * Cn;          // 3,145,728 elements per tensor
constexpr int NDn = Nn * Dn;               // 65,536
constexpr int WQ_ELE = 3 * Cn * Cn;        // 1,769,472
constexpr int WP_ELE = Cn * Cn;            // 589,824

typedef __attribute__((ext_vector_type(8))) short bf16x8;
typedef __attribute__((ext_vector_type(4))) float f32x4;

__device__ __forceinline__ unsigned short f2bf(float f) {
    union { float f; unsigned u; } v; v.f = f;
    unsigned r = v.u + 0x7fffu + ((v.u >> 16) & 1u);   // RNE
    return (unsigned short)(r >> 16);
}
__device__ __forceinline__ float bf2f(unsigned short b) {
    union { unsigned u; float f; } v; v.u = ((unsigned)b) << 16;
    return v.f;
}
__device__ __forceinline__ bf16x8 ldfrag(const unsigned short* base, int boff) {
    return *(const bf16x8*)((const char*)base + boff);
}
#define MFMA(a, b, c) __builtin_amdgcn_mfma_f32_16x16x32_bf16((a), (b), (c), 0, 0, 0)

// ---------------------------------------------------------------------------
// Workspace layout (ushort units), total 16*SEG ushorts:
//  region A (off 0)      : [INh0|INl0|INh1|INl1] -> reused as [xh|xl|xjh|xjl]
//  region B (off 4*SEG)  : qkv t2=0..5, hi at (2*t2)*SEG, lo +SEG.
//                          v/vj (t2=2,5) stored TRANSPOSED [bh][d][n].
//                          After attn, head of region B reused for W_proj split.
//  d_out: used as scratch for W_qkv hi/lo split until final GEMM overwrites it.
// ---------------------------------------------------------------------------

// fp32 -> (hi,lo) bf16 split of input / input_jvp.
__global__ __launch_bounds__(256)
void conv_k(const float* __restrict__ a0, const float* __restrict__ a1,
            unsigned short* __restrict__ dst)
{
    const int P = SEG / 4;
    const int j = blockIdx.x * 256 + threadIdx.x;
    const int arr = j / P;
    const int i = (j - arr * P) * 4;
    const float* __restrict__ src = arr ? a1 : a0;
    const float4 f = *(const float4*)(src + i);
    const float ff[4] = {f.x, f.y, f.z, f.w};
    ushort4 h, lo;
#pragma unroll
    for (int t = 0; t < 4; ++t) {
        const unsigned short hv = f2bf(ff[t]);
        (&h.x)[t] = hv;
        (&lo.x)[t] = f2bf(ff[t] - bf2f(hv));
    }
    *(ushort4*)(dst + (size_t)(2 * arr) * SEG + i) = h;
    *(ushort4*)(dst + (size_t)(2 * arr + 1) * SEG + i) = lo;
}

// fp32 -> (hi,lo) bf16 split, flat array (for weights).
__global__ __launch_bounds__(256)
void conv_w(const float* __restrict__ src, unsigned short* __restrict__ dh,
            unsigned short* __restrict__ dl)
{
    const int i = (blockIdx.x * 256 + threadIdx.x) * 4;
    const float4 f = *(const float4*)(src + i);
    const float ff[4] = {f.x, f.y, f.z, f.w};
    ushort4 h, lo;
#pragma unroll
    for (int t = 0; t < 4; ++t) {
        const unsigned short hv = f2bf(ff[t]);
        (&h.x)[t] = hv;
        (&lo.x)[t] = f2bf(ff[t] - bf2f(hv));
    }
    *(ushort4*)(dh + i) = h;
    *(ushort4*)(dl + i) = lo;
}

// ---------------------------------------------------------------------------
// Split-bf16 MFMA GEMM: Y = A @ W^T. A and W both pre-split (hi/lo bf16).
// 256x256 tile, BK=32, 512 threads (8 waves as 2x4 of 128x64 wave-tiles).
// Halves L2/L3 panel re-read traffic vs 128x128. T14 reg-prefetch of next
// k-tile during MFMA. XOR swizzle: chunk ^= row&3 (64B rows, 2-way max).
// MODE 0: scatter q/k/v to region B (SCALE on q; v/vj transposed [d][n]).
// MODE 1: out[z*SEG + row*768 + col] = acc (+bias for z==0).
// ---------------------------------------------------------------------------
template<int MODE>
__global__ __launch_bounds__(512, 2)
void gemm_mfma(const unsigned short* __restrict__ Abase,
               const unsigned short* __restrict__ Wh,
               const unsigned short* __restrict__ Wl,
               const float* __restrict__ bias,
               unsigned short* __restrict__ qkv, float* __restrict__ out)
{
    __shared__ unsigned short sAh[256 * 32];   // 16 KB each, 64 KB total
    __shared__ unsigned short sAl[256 * 32];
    __shared__ unsigned short sBh[256 * 32];
    __shared__ unsigned short sBl[256 * 32];

    const int tid = threadIdx.x;
    const int z = blockIdx.z;
    const int row0 = blockIdx.y << 8;
    const int col0 = blockIdx.x << 8;
    const int l = tid & 63, w = tid >> 6;
    const int wr = w >> 2, wc = w & 3;          // wave-tile: rows 128*wr, cols 64*wc
    const int h4 = l >> 4, l15 = l & 15;
    const int swz = (h4 ^ (l15 & 3)) << 4;      // frag-read swizzle (const per lane)
    const int srow = tid >> 2;                  // staging rows srow, srow+128
    const int sch = tid & 3;                    // chunk 0..3 (8 ushorts each)

    const unsigned short* __restrict__ Ah = Abase + (size_t)(2 * z) * SEG;
    const unsigned short* __restrict__ Al = Abase + (size_t)(2 * z + 1) * SEG;

    f32x4 acc[8][4];
#pragma unroll
    for (int m = 0; m < 8; ++m)
#pragma unroll
        for (int n = 0; n < 4; ++n)
            acc[m][n] = (f32x4){0.f, 0.f, 0.f, 0.f};

    bf16x8 pA0h, pA0l, pA1h, pA1l, pB0h, pB0l, pB1h, pB1l;

#define G_LOADT(K0_) {                                                         \
    const size_t gA0 = (size_t)(row0 + srow) * Cn + (K0_) + 8 * sch;           \
    const size_t gA1 = (size_t)(row0 + srow + 128) * Cn + (K0_) + 8 * sch;     \
    const size_t gB0 = (size_t)(col0 + srow) * Cn + (K0_) + 8 * sch;           \
    const size_t gB1 = (size_t)(col0 + srow + 128) * Cn + (K0_) + 8 * sch;     \
    pA0h = *(const bf16x8*)(Ah + gA0);  pA0l = *(const bf16x8*)(Al + gA0);     \
    pA1h = *(const bf16x8*)(Ah + gA1);  pA1l = *(const bf16x8*)(Al + gA1);     \
    pB0h = *(const bf16x8*)(Wh + gB0);  pB0l = *(const bf16x8*)(Wl + gB0);     \
    pB1h = *(const bf16x8*)(Wh + gB1);  pB1l = *(const bf16x8*)(Wl + gB1);     \
    }

    const int ba0 = srow * 64 + ((sch ^ (srow & 3)) << 4);
    const int ba1 = (srow + 128) * 64 + ((sch ^ (srow & 3)) << 4);  // (srow+128)&3==srow&3

    G_LOADT(0);

    for (int k0 = 0; k0 < Cn; k0 += 32) {
        __syncthreads();
        *(bf16x8*)((char*)sAh + ba0) = pA0h;  *(bf16x8*)((char*)sAl + ba0) = pA0l;
        *(bf16x8*)((char*)sAh + ba1) = pA1h;  *(bf16x8*)((char*)sAl + ba1) = pA1l;
        *(bf16x8*)((char*)sBh + ba0) = pB0h;  *(bf16x8*)((char*)sBl + ba0) = pB0l;
        *(bf16x8*)((char*)sBh + ba1) = pB1h;  *(bf16x8*)((char*)sBl + ba1) = pB1l;
        const int kn = (k0 + 32 < Cn) ? k0 + 32 : 0;
        G_LOADT(kn);                            // T14: hide under MFMA phase
        __syncthreads();

        bf16x8 bh[4], bl[4];
#pragma unroll
        for (int n = 0; n < 4; ++n) {
            const int boff = (64 * wc + 16 * n + l15) * 64 + swz;
            bh[n] = ldfrag(sBh, boff);
            bl[n] = ldfrag(sBl, boff);
        }
#pragma unroll
        for (int mh = 0; mh < 2; ++mh) {
            bf16x8 ah[4], al[4];
#pragma unroll
            for (int mi = 0; mi < 4; ++mi) {
                const int m = mh * 4 + mi;
                const int boff = (128 * wr + 16 * m + l15) * 64 + swz;
                ah[mi] = ldfrag(sAh, boff);
                al[mi] = ldfrag(sAl, boff);
            }
#pragma unroll
            for (int mi = 0; mi < 4; ++mi)
#pragma unroll
                for (int n = 0; n < 4; ++n) {
                    f32x4 a = acc[mh * 4 + mi][n];
                    a = MFMA(ah[mi], bh[n], a);
                    a = MFMA(ah[mi], bl[n], a);
                    a = MFMA(al[mi], bh[n], a);
                    acc[mh * 4 + mi][n] = a;
                }
        }
    }

    if (MODE == 0) {
#pragma unroll
        for (int n = 0; n < 4; ++n) {
            const int colb = col0 + 64 * wc + 16 * n;
            const int t = colb / Cn;            // uniform per block (768 % 256 == 0)
            const int rem = colb - t * Cn;
            const int hh = rem >> 6;
            const int d = (rem & 63) + l15;
            const float sc = (t == 0) ? SCALE_Q : 1.0f;
            const int t2 = t + 3 * z;
            unsigned short* __restrict__ dh = qkv + (size_t)(2 * t2) * SEG;
            unsigned short* __restrict__ dl = dh + SEG;
#pragma unroll
            for (int m = 0; m < 8; ++m)
#pragma unroll
                for (int r = 0; r < 4; ++r) {
                    const int row = row0 + 128 * wr + 16 * m + 4 * h4 + r;
                    const int b = row >> 10, nq = row & 1023;
                    const size_t ad = (size_t)(b * Hn + hh) * NDn +
                        (t == 2 ? (size_t)d * Nn + nq     // v/vj transposed [d][n]
                                : (size_t)nq * 64 + d);
                    const float vv = acc[m][n][r] * sc;
                    const unsigned short hv = f2bf(vv);
                    dh[ad] = hv;
                    dl[ad] = f2bf(vv - bf2f(hv));
                }
        }
    } else {
#pragma unroll
        for (int n = 0; n < 4; ++n) {
            const int col = col0 + 64 * wc + 16 * n + l15;
            const float bi = (z == 0) ? bias[col] : 0.0f;
#pragma unroll
            for (int m = 0; m < 8; ++m)
#pragma unroll
                for (int r = 0; r < 4; ++r) {
                    const int row = row0 + 128 * wr + 16 * m + 4 * h4 + r;
                    out[(size_t)z * SEG + (size_t)row * Cn + col] = acc[m][n][r] + bi;
                }
        }
    }
}

// ---------------------------------------------------------------------------
// MFMA attention + softmax-JVP (verified; byte-identical to round 7).
// ---------------------------------------------------------------------------
__global__ __launch_bounds__(256, 2)
void attn_mfma(unsigned short* __restrict__ wsu)
{
    __shared__ unsigned short sKV[4][64 * 64];     // 32 KB, XOR-swizzled
    __shared__ unsigned short sP[4][4][16 * 64];   // 32 KB, wave-private

    const int tid = threadIdx.x;
    const int l = tid & 63;
    const int w = tid >> 6;
    const int h4 = l >> 4;
    const int l15 = l & 15;
    const int sw = (l15 & 7) << 4;
    const int rA = tid >> 3;          // staging row 0..31 (and rA+32)
    const int ss = tid & 7;
    const int rB = rA + 32;

    const int bh = blockIdx.x;
    const int r0 = blockIdx.y << 6;

    const unsigned short* __restrict__ Bq = wsu + 4 * (size_t)SEG + (size_t)bh * NDn;
    const unsigned short* __restrict__ qh   = Bq;                    // t2=0
    const unsigned short* __restrict__ kh   = Bq + 2 * (size_t)SEG;  // t2=1
    const unsigned short* __restrict__ vth  = Bq + 4 * (size_t)SEG;  // t2=2 [d][n]
    const unsigned short* __restrict__ qjh  = Bq + 6 * (size_t)SEG;  // t2=3
    const unsigned short* __restrict__ kjh  = Bq + 8 * (size_t)SEG;  // t2=4
    const unsigned short* __restrict__ vjth = Bq + 10 * (size_t)SEG; // t2=5 [d][n]

    // ---- Prologue: Q/QJ fragments
    bf16x8 qhi[2], qlo[2], qjhi[2], qjlo[2];
    {
        const int qrow = r0 + w * 16 + l15;
#pragma unroll
        for (int c = 0; c < 2; ++c) {
            const size_t o = (size_t)qrow * 64 + c * 32 + h4 * 8;
            qhi[c] = *(const bf16x8*)(qh + o);
            qlo[c] = *(const bf16x8*)(qh + SEG + o);
            qjhi[c] = *(const bf16x8*)(qjh + o);
            qjlo[c] = *(const bf16x8*)(qjh + SEG + o);
        }
    }

    f32x4 mold = {-3.0e38f, -3.0e38f, -3.0e38f, -3.0e38f};
    f32x4 l_run = {0.f, 0.f, 0.f, 0.f};
    f32x4 ar_run = {0.f, 0.f, 0.f, 0.f};
    f32x4 ax[4], ac[4], ad[4];
#pragma unroll
    for (int ds = 0; ds < 4; ++ds) {
        ax[ds] = (f32x4){0.f, 0.f, 0.f, 0.f};
        ac[ds] = (f32x4){0.f, 0.f, 0.f, 0.f};
        ad[ds] = (f32x4){0.f, 0.f, 0.f, 0.f};
    }

    bf16x8 kr0[4], kr1[4], vr0[4], vr1[4];
    const int ba = rA * 128 + ((ss ^ (rA & 7)) << 4);
    const int bb = rB * 128 + ((ss ^ (rA & 7)) << 4);   // rB&7 == rA&7

#define A_LOADK(JT_) {                                                         \
    const size_t ga = (size_t)((JT_) + rA) * 64 + 8 * ss;                      \
    const size_t gb = (size_t)((JT_) + rB) * 64 + 8 * ss;                      \
    kr0[0] = *(const bf16x8*)(kh + ga);        kr1[0] = *(const bf16x8*)(kh + gb); \
    kr0[1] = *(const bf16x8*)(kh + SEG + ga);  kr1[1] = *(const bf16x8*)(kh + SEG + gb); \
    kr0[2] = *(const bf16x8*)(kjh + ga);       kr1[2] = *(const bf16x8*)(kjh + gb); \
    kr0[3] = *(const bf16x8*)(kjh + SEG + ga); kr1[3] = *(const bf16x8*)(kjh + SEG + gb); }

#define A_LOADV(JT_) {                                                         \
    const size_t ga = (size_t)rA * Nn + (JT_) + 8 * ss;                        \
    const size_t gb = (size_t)rB * Nn + (JT_) + 8 * ss;                        \
    vr0[0] = *(const bf16x8*)(vth + ga);        vr1[0] = *(const bf16x8*)(vth + gb); \
    vr0[1] = *(const bf16x8*)(vth + SEG + ga);  vr1[1] = *(const bf16x8*)(vth + SEG + gb); \
    vr0[2] = *(const bf16x8*)(vjth + ga);       vr1[2] = *(const bf16x8*)(vjth + gb); \
    vr0[3] = *(const bf16x8*)(vjth + SEG + ga); vr1[3] = *(const bf16x8*)(vjth + SEG + gb); }

#define A_WRITE(R0_, R1_) {                                                    \
    *(bf16x8*)((char*)sKV[0] + ba) = R0_[0]; *(bf16x8*)((char*)sKV[0] + bb) = R1_[0]; \
    *(bf16x8*)((char*)sKV[1] + ba) = R0_[1]; *(bf16x8*)((char*)sKV[1] + bb) = R1_[1]; \
    *(bf16x8*)((char*)sKV[2] + ba) = R0_[2]; *(bf16x8*)((char*)sKV[2] + bb) = R1_[2]; \
    *(bf16x8*)((char*)sKV[3] + ba) = R0_[3]; *(bf16x8*)((char*)sKV[3] + bb) = R1_[3]; }

    A_LOADK(0);

    for (int jt = 0; jt < Nn; jt += 64) {
        __syncthreads();                       // (a) sKV free (prev PV done)
        A_WRITE(kr0, kr1);
        __syncthreads();                       // (b)

        // ---- S, DM via split-bf16 MFMA
        f32x4 S[4], DM[4];
        __builtin_amdgcn_s_setprio(1);
#pragma unroll
        for (int kt = 0; kt < 4; ++kt) {
            f32x4 s = {0.f, 0.f, 0.f, 0.f};
            f32x4 dm = {0.f, 0.f, 0.f, 0.f};
#pragma unroll
            for (int c = 0; c < 2; ++c) {
                const int boff = (l15 + (kt << 4)) * 128 + (((h4 << 4) | (c << 6)) ^ sw);
                const bf16x8 khi = ldfrag(sKV[0], boff);
                const bf16x8 klo = ldfrag(sKV[1], boff);
                const bf16x8 jhi = ldfrag(sKV[2], boff);
                const bf16x8 jlo = ldfrag(sKV[3], boff);
                s = MFMA(qhi[c], khi, s);
                s = MFMA(qhi[c], klo, s);
                s = MFMA(qlo[c], khi, s);
                dm = MFMA(qjhi[c], khi, dm);
                dm = MFMA(qjhi[c], klo, dm);
                dm = MFMA(qjlo[c], khi, dm);
                dm = MFMA(qhi[c], jhi, dm);
                dm = MFMA(qhi[c], jlo, dm);
                dm = MFMA(qlo[c], jhi, dm);
            }
            S[kt] = s; DM[kt] = dm;
        }
        __builtin_amdgcn_s_setprio(0);

        // T14: issue V(jt) + next K loads; latency hides under softmax
        A_LOADV(jt);
        A_LOADK((jt + 64) & (Nn - 1));

        // ---- online softmax update
        f32x4 tmax, mnew, alpha;
#pragma unroll
        for (int r = 0; r < 4; ++r)
            tmax[r] = fmaxf(fmaxf(S[0][r], S[1][r]), fmaxf(S[2][r], S[3][r]));
#pragma unroll
        for (int m = 1; m < 16; m <<= 1)
#pragma unroll
            for (int r = 0; r < 4; ++r)
                tmax[r] = fmaxf(tmax[r], __shfl_xor(tmax[r], m));
#pragma unroll
        for (int r = 0; r < 4; ++r) {
            mnew[r] = fmaxf(mold[r], tmax[r]);
            alpha[r] = __expf(mold[r] - mnew[r]);
            mold[r] = mnew[r];
        }
        f32x4 lsum = {0.f, 0.f, 0.f, 0.f};
        f32x4 arsum = {0.f, 0.f, 0.f, 0.f};
#pragma unroll
        for (int kt = 0; kt < 4; ++kt) {
            const int key = (kt << 4) + l15;
#pragma unroll
            for (int r = 0; r < 4; ++r) {
                const float p = __expf(S[kt][r] - mnew[r]);
                const float pd = p * DM[kt][r];
                lsum[r] += p;
                arsum[r] += pd;
                const int qq = (h4 << 2) + r;
                const int boff = qq * 128 +
                    (((key & 7) << 1) | ((((key >> 3) ^ (qq & 7)) << 4)));
                const unsigned short ph = f2bf(p);
                const unsigned short pdh = f2bf(pd);
                *(unsigned short*)((char*)sP[w][0] + boff) = ph;
                *(unsigned short*)((char*)sP[w][1] + boff) = f2bf(p - bf2f(ph));
                *(unsigned short*)((char*)sP[w][2] + boff) = pdh;
                *(unsigned short*)((char*)sP[w][3] + boff) = f2bf(pd - bf2f(pdh));
            }
        }
#pragma unroll
        for (int r = 0; r < 4; ++r) {
            l_run[r] = l_run[r] * alpha[r] + lsum[r];
            ar_run[r] = ar_run[r] * alpha[r] + arsum[r];
        }
#pragma unroll
        for (int ds = 0; ds < 4; ++ds) {
            ax[ds] *= alpha; ac[ds] *= alpha; ad[ds] *= alpha;
        }

        __syncthreads();                       // (c) all waves done K reads
        A_WRITE(vr0, vr1);                     // V^T tile, pure b128 copies
        __syncthreads();                       // (d)

        // ---- PV: x += P.V ; xc += P.VJ ; xd += (P*dm).V
        __builtin_amdgcn_s_setprio(1);
#pragma unroll
        for (int kc = 0; kc < 2; ++kc) {
            const int pxo = ((h4 << 4) | (kc << 6)) ^ sw;
            const bf16x8 phi = ldfrag(sP[w][0], l15 * 128 + pxo);
            const bf16x8 plo = ldfrag(sP[w][1], l15 * 128 + pxo);
            const bf16x8 dhi = ldfrag(sP[w][2], l15 * 128 + pxo);
            const bf16x8 dlo = ldfrag(sP[w][3], l15 * 128 + pxo);
#pragma unroll
            for (int ds = 0; ds < 4; ++ds) {
                const int boff = (l15 + (ds << 4)) * 128 + pxo;
                const bf16x8 vhi = ldfrag(sKV[0], boff);
                const bf16x8 vlo = ldfrag(sKV[1], boff);
                const bf16x8 wjh = ldfrag(sKV[2], boff);
                const bf16x8 wjl = ldfrag(sKV[3], boff);
                ax[ds] = MFMA(phi, vhi, ax[ds]);
                ax[ds] = MFMA(phi, vlo, ax[ds]);
                ax[ds] = MFMA(plo, vhi, ax[ds]);
                ac[ds] = MFMA(phi, wjh, ac[ds]);
                ac[ds] = MFMA(phi, wjl, ac[ds]);
                ac[ds] = MFMA(plo, wjh, ac[ds]);
                ad[ds] = MFMA(dhi, vhi, ad[ds]);
                ad[ds] = MFMA(dhi, vlo, ad[ds]);
                ad[ds] = MFMA(dlo, vhi, ad[ds]);
            }
        }
        __builtin_amdgcn_s_setprio(0);
    }

    // ---- Epilogue: normalize, JVP correction, store x/xj as hi/lo bf16
#pragma unroll
    for (int m = 1; m < 16; m <<= 1)
#pragma unroll
        for (int r = 0; r < 4; ++r) {
            l_run[r] += __shfl_xor(l_run[r], m);
            ar_run[r] += __shfl_xor(ar_run[r], m);
        }
    const int b = bh / Hn;
    const int hh = bh - b * Hn;
    unsigned short* __restrict__ xh = wsu;
    unsigned short* __restrict__ xl = wsu + (size_t)SEG;
    unsigned short* __restrict__ xjh = wsu + 2 * (size_t)SEG;
    unsigned short* __restrict__ xjl = wsu + 3 * (size_t)SEG;
#pragma unroll
    for (int r = 0; r < 4; ++r) {
        const int qg = r0 + w * 16 + (h4 << 2) + r;
        const float invl = 1.0f / l_run[r];
        const float rowv = ar_run[r] * invl;
        const size_t base = ((size_t)(b * Nn + qg)) * Cn + hh * Dn + l15;
#pragma unroll
        for (int ds = 0; ds < 4; ++ds) {
            const float x = ax[ds][r] * invl;
            const float xjv = fmaf(-rowv, x, (ad[ds][r] + ac[ds][r]) * invl);
            const size_t ad2 = base + ds * 16;
            const unsigned short h0 = f2bf(x);
            xh[ad2] = h0;
            xl[ad2] = f2bf(x - bf2f(h0));
            const unsigned short h1 = f2bf(xjv);
            xjh[ad2] = h1;
            xjl[ad2] = f2bf(xjv - bf2f(h1));
        }
    }
}

extern "C" void kernel_launch(void* const* d_in, const int* in_sizes, int n_in,
                              void* d_out, int out_size, void* d_ws, size_t ws_size,
                              hipStream_t stream)
{
    const float* input  = (const float*)d_in[0];
    const float* inputj = (const float*)d_in[1];
    const float* W_qkv  = (const float*)d_in[2];
    const float* W_proj = (const float*)d_in[3];
    const float* b_proj = (const float*)d_in[4];
    float* out = (float*)d_out;
    unsigned short* wsu = (unsigned short*)d_ws;
    unsigned short* regA = wsu;                      // IN splits -> x splits
    unsigned short* regB = wsu + 4 * (size_t)SEG;    // qkv splits (12 segs)
    unsigned short* wqh = (unsigned short*)d_out;    // W_qkv split scratch in d_out
    unsigned short* wql = wqh + (size_t)WQ_ELE;      // (overwritten by final GEMM)
    unsigned short* wph = regB;                      // W_proj split (after attn)
    unsigned short* wpl = wph + (size_t)WP_ELE;

    // 1) split inputs and W_qkv into hi/lo bf16
    conv_k<<<2 * (SEG / 4) / 256, 256, 0, stream>>>(input, inputj, regA);
    conv_w<<<(WQ_ELE / 4) / 256, 256, 0, stream>>>(W_qkv, wqh, wql);
    // 2) qkv = IN @ W_qkv^T  (MFMA; scatter hi/lo, scale q, transpose v)
    gemm_mfma<0><<<dim3(9, 16, 2), 512, 0, stream>>>(regA, wqh, wql, nullptr,
                                                     regB, nullptr);
    // 3) fused attention + softmax JVP (writes x/xj hi/lo into region A)
    attn_mfma<<<dim3(48, 16), 256, 0, stream>>>(wsu);
    // 4) split W_proj (region B now free), then out = x @ W_proj^T (+bias)
    conv_w<<<(WP_ELE / 4) / 256, 256, 0, stream>>>(W_proj, wph, wpl);
    gemm_mfma<1><<<dim3(3, 16, 2), 512, 0, stream>>>(regA, wph, wpl, b_proj,
                                                     nullptr, out);
}